// Round 4
// baseline (157.788 us; speedup 1.0000x reference)
//
#include <hip/hip_runtime.h>
#include <math.h>

#define B 8
#define SQ 128
#define SK 128
#define IVD 32
#define DIM 32
#define EV 64
#define H 8
#define NH 128
#define DK 8
#define TQ 2
#define KG 8      // k-groups in weighted-sum phase (16 k each)
#define PAD 132   // transposed leading dim: SK + 4 floats
#define NBLK 512  // == B*SQ/TQ; exactly 2 blocks/CU on 256 CUs (co-resident)
#define QSCALE 0.3535533905932738f

__device__ __forceinline__ float fast_tanh(float x) {
    const float xc = fminf(fmaxf(x, -10.f), 10.f);
    const float t = __expf(2.f * xc);
    return (t - 1.f) / (t + 1.f);
}

// Single fused kernel. Block blk:
//   Phase A1: q rows 2blk,2blk+1 -> MLP+proj -> LDS qs_s (pre-scaled by 1/sqrt(DK))
//   Phase A2: k rows 2blk,2blk+1 -> MLP+proj -> global kproj; release flag
//   Phase A3: impute rows 2blk,2blk+1 -> qd   (overlaps other blocks' A2)
//   Stage value/mask into LDS (overlaps barrier wait)
//   Acquire-poll all 512 flags (grid barrier; 2 blocks/CU * 256 CUs == grid, no deadlock)
//   Phase B: masked-softmax attention + wo GEMV for q rows 2blk,2blk+1
__global__ __launch_bounds__(256, 2) void mega_kernel(
    const float* __restrict__ qv, const float* __restrict__ kv,
    const float* __restrict__ w1, const float* __restrict__ b1,
    const float* __restrict__ w2,
    const float* __restrict__ wq, const float* __restrict__ bqv,
    const float* __restrict__ wk, const float* __restrict__ bkv,
    const float* __restrict__ value, const int* __restrict__ mask,
    const float* __restrict__ wo, const float* __restrict__ bo,
    const float* __restrict__ imp,
    const float* __restrict__ wd1, const float* __restrict__ bd1,
    const float* __restrict__ ln_g, const float* __restrict__ ln_b,
    const float* __restrict__ wd2, const float* __restrict__ bd2,
    float* __restrict__ kproj, int* __restrict__ flags,
    float* __restrict__ y, float* __restrict__ qd)
{
    const int blk = blockIdx.x;
    const int tid = threadIdx.x;
    const int b = blk >> 6;               // batch
    const int q0 = (blk & 63) * TQ;       // this block's q rows == its phase-A q rows
    const int r0 = 2 * blk;               // global row pair index (q / k / impute)

    __shared__ __align__(16) float qs_s[TQ * EV];   // persists A->B
    __shared__ __align__(16) char smem[62464];      // phase A / phase B union

    // phase-A aliases (low 4 KB)
    float* xs   = (float*)smem;             // [2][IVD]      256 B
    float* h1   = (float*)(smem + 256);     // [2][NH]      1024 B
    float* ev   = (float*)(smem + 1280);    // [2][EV]       512 B
    float* part = (float*)(smem + 1792);    // [256]        1024 B
    float* red  = (float*)(smem + 2816);    // [4]            16 B
    float* h1b  = (float*)(smem + 2832);    // [2][NH]      1024 B
    // phase-B aliases
    float*  sc    = (float*)(smem);          // [TQ*H*SK]   8192 B  @0
    float*  mvt   = (float*)(smem + 8192);   // [DIM*PAD]  16896 B
    float*  mmt   = (float*)(smem + 25088);  // [DIM*PAD]  16896 B
    float2* prt   = (float2*)(smem + 41984); // [H*KG*DIM] 16384 B
    float*  xr    = (float*)(smem + 58368);  // [TQ*H*DIM]  2048 B
    float*  ypart = (float*)(smem + 60416);  // [2*TQ*NH]   2048 B

    const int col = tid & 127, rrow = tid >> 7;     // 2-row decomposition
    const int o = tid & 63, hf = (tid >> 6) & 1;    // 64-out x 2-half decomposition

    // ---------------- Phase A1/A2: q then k projection pairs ----------------
    #pragma unroll
    for (int pass = 0; pass < 2; ++pass) {
        const float* src = pass ? kv : qv;
        const float* wp  = pass ? wk : wq;
        if (tid < 2 * IVD) xs[tid] = src[r0 * IVD + tid];
        __syncthreads();
        {   // GEMV1: h1 = tanh(x @ w1 + b1); one (row,col) per thread
            float a = b1[col];
            #pragma unroll
            for (int i = 0; i < IVD; ++i) a += xs[rrow * IVD + i] * w1[i * NH + col];
            h1[rrow * NH + col] = fast_tanh(a);
        }
        __syncthreads();
        {   // GEMV2: ev = h1 @ w2 ; dot split in 2 halves
            float c = 0.f;
            #pragma unroll 8
            for (int i = hf * 64; i < hf * 64 + 64; ++i) c += h1[rrow * NH + i] * w2[i * EV + o];
            part[tid] = c;
        }
        __syncthreads();
        if (tid < 128) {
            const int rw = tid >> 6, oo = tid & 63;
            ev[rw * EV + oo] = part[rw * 128 + oo] + part[rw * 128 + 64 + oo];
        }
        __syncthreads();
        {   // GEMV3: proj = ev @ wp + bp
            float c = 0.f;
            #pragma unroll 8
            for (int j = hf * 32; j < hf * 32 + 32; ++j) c += ev[rrow * EV + j] * wp[j * EV + o];
            part[tid] = c;
        }
        __syncthreads();
        if (tid < 128) {
            const int rw = tid >> 6, oo = tid & 63;
            const float v = part[rw * 128 + oo] + part[rw * 128 + 64 + oo];
            if (pass == 0) qs_s[rw * EV + oo] = (v + bqv[oo]) * QSCALE;  // stays in LDS
            else           kproj[(r0 + rw) * EV + oo] = v + bkv[oo];
        }
        __syncthreads();
    }
    // kproj written & drained (barrier implies vmcnt(0)); publish to other blocks
    if (tid == 0)
        __hip_atomic_store(&flags[blk], 1, __ATOMIC_RELEASE, __HIP_MEMORY_SCOPE_AGENT);

    // ---------------- Phase A3: impute rows r0, r0+1 (overlaps barrier) ----------------
    if (tid < IVD) xs[tid] = imp[r0 * (IVD / 2) + tid];   // 2 rows x 16
    __syncthreads();
    {
        float acc = bd1[col];
        #pragma unroll
        for (int i = 0; i < IVD / 2; ++i) acc += xs[rrow * (IVD / 2) + i] * wd1[i * NH + col];

        const int wv = tid >> 6, ln = tid & 63;   // waves 2*rrow, 2*rrow+1 hold row rrow
        float s = acc;
        #pragma unroll
        for (int off = 32; off > 0; off >>= 1) s += __shfl_down(s, off, 64);
        if (ln == 0) red[wv] = s;
        __syncthreads();
        const float mean = (red[rrow * 2] + red[rrow * 2 + 1]) * (1.f / NH);
        const float diff = acc - mean;
        float s2 = diff * diff;
        __syncthreads();
        #pragma unroll
        for (int off = 32; off > 0; off >>= 1) s2 += __shfl_down(s2, off, 64);
        if (ln == 0) red[wv] = s2;
        __syncthreads();
        const float var = (red[rrow * 2] + red[rrow * 2 + 1]) * (1.f / NH);  // ddof=0
        const float lnv = diff * rsqrtf(var + 1e-5f) * ln_g[col] + ln_b[col];
        h1b[rrow * NH + col] = fmaxf(lnv, 0.f);
    }
    __syncthreads();
    {
        float c = bd2[col];
        #pragma unroll 8
        for (int j = 0; j < NH; ++j) c += h1b[rrow * NH + j] * wd2[j * NH + col];
        qd[(r0 + rrow) * NH + col] = c;
    }

    // ---------------- Stage value/mask (independent of other blocks) ----------------
    for (int idx = tid; idx < SK * DIM; idx += 256) {
        const int k = idx >> 5, d = idx & 31;
        const float v = value[b * SK * DIM + idx];
        const float m = (float)mask[b * SK * DIM + idx];
        mvt[d * PAD + k] = v * m;
        mmt[d * PAD + k] = m;
    }

    // ---------------- Grid barrier: wait for all kproj producers ----------------
    if (tid < 128) {
        const int base = tid * 4;
        for (;;) {
            int ok = 1;
            #pragma unroll
            for (int j = 0; j < 4; ++j)
                ok &= (__hip_atomic_load(&flags[base + j], __ATOMIC_ACQUIRE,
                                         __HIP_MEMORY_SCOPE_AGENT) == 1);
            if (ok) break;
            __builtin_amdgcn_s_sleep(8);
        }
    }
    __syncthreads();

    // ---------------- Phase B: scores -> exp (no max: |s| small, ratio-identical) ----
    #pragma unroll
    for (int i = 0; i < (TQ * H * SK) / 256; ++i) {
        const int p = tid + i * 256;
        const int q = p >> 10, rem = p & 1023, h = rem >> 7, k = rem & 127;
        const float4* kr = (const float4*)(kproj + (b * SK + k) * EV + h * DK);
        const float4* qq = (const float4*)(qs_s + q * EV + h * DK);
        const float4 k0 = kr[0], k1 = kr[1], qa = qq[0], qb = qq[1];
        const float s = qa.x * k0.x + qa.y * k0.y + qa.z * k0.z + qa.w * k0.w
                      + qb.x * k1.x + qb.y * k1.y + qb.z * k1.z + qb.w * k1.w;
        sc[p] = __expf(s);
    }
    __syncthreads();

    // weighted masked sums: thread owns (d, kg); value/mask slice in registers
    {
        const int d = tid & 31, kg = tid >> 5;
        float4 vv[4], mq[4];
        const float4* vp = (const float4*)&mvt[d * PAD + kg * 16];
        const float4* mp = (const float4*)&mmt[d * PAD + kg * 16];
        #pragma unroll
        for (int j = 0; j < 4; ++j) { vv[j] = vp[j]; mq[j] = mp[j]; }

        #pragma unroll
        for (int q = 0; q < TQ; ++q) {
            #pragma unroll
            for (int h = 0; h < H; ++h) {
                const float4* sp = (const float4*)&sc[(q * H + h) * SK + kg * 16];
                float num = 0.f, den = 0.f;
                #pragma unroll
                for (int j = 0; j < 4; ++j) {
                    const float4 s = sp[j];
                    num += s.x * vv[j].x + s.y * vv[j].y + s.z * vv[j].z + s.w * vv[j].w;
                    den += s.x * mq[j].x + s.y * mq[j].y + s.z * mq[j].z + s.w * mq[j].w;
                }
                prt[(h * KG + kg) * DIM + d] = make_float2(num, den);
            }
            __syncthreads();
            {   // reduce 8 k-groups; thread -> (h = tid>>5, d = tid&31)
                const int h = tid >> 5;
                float num = 0.f, den = 0.f;
                #pragma unroll
                for (int g = 0; g < KG; ++g) {
                    const float2 p2 = prt[(h * KG + g) * DIM + d];
                    num += p2.x; den += p2.y;
                }
                xr[q * (H * DIM) + tid] = num / den;
            }
            __syncthreads();
        }
    }

    // y = x @ wo + bo : 256-dot split in halves, wo load shared across TQ rows
    {
        const int n = tid & 127, half = tid >> 7;
        const float* wop = wo + half * 128 * NH + n;
        const float* x0 = xr + half * 128;
        const float* x1 = xr + (H * DIM) + half * 128;
        float a0 = 0.f, a1 = 0.f;
        #pragma unroll 4
        for (int j = 0; j < 128; ++j) {
            const float w = wop[j * NH];
            a0 += w * x0[j];
            a1 += w * x1[j];
        }
        ypart[half * (TQ * NH) + 0 * NH + n] = a0;
        ypart[half * (TQ * NH) + 1 * NH + n] = a1;
    }
    __syncthreads();
    {
        const int q = tid >> 7, n = tid & 127;
        y[(b * SQ + q0 + q) * NH + n] =
            ypart[q * NH + n] + ypart[TQ * NH + q * NH + n] + bo[n];
    }
}

extern "C" void kernel_launch(void* const* d_in, const int* in_sizes, int n_in,
                              void* d_out, int out_size, void* d_ws, size_t ws_size,
                              hipStream_t stream) {
    const float* query_value = (const float*)d_in[0];
    const float* key_value   = (const float*)d_in[1];
    const float* value       = (const float*)d_in[2];
    const float* impute      = (const float*)d_in[3];
    const int*   emb_mask    = (const int*)d_in[4];
    const float* w1   = (const float*)d_in[5];
    const float* b1   = (const float*)d_in[6];
    const float* w2   = (const float*)d_in[7];
    const float* wq   = (const float*)d_in[8];
    const float* bq   = (const float*)d_in[9];
    const float* wk   = (const float*)d_in[10];
    const float* bk   = (const float*)d_in[11];
    const float* wo   = (const float*)d_in[12];
    const float* bo   = (const float*)d_in[13];
    const float* wd1  = (const float*)d_in[14];
    const float* bd1  = (const float*)d_in[15];
    const float* ln_g = (const float*)d_in[16];
    const float* ln_b = (const float*)d_in[17];
    const float* wd2  = (const float*)d_in[18];
    const float* bd2  = (const float*)d_in[19];

    float* y  = (float*)d_out;                 // (B,SQ,NH)
    float* qd = y + B * SQ * NH;               // (B,SQ,NH)

    float* kproj = (float*)d_ws;                               // (B,SK,EV) 256 KB
    int*   flags = (int*)((char*)d_ws + B * SK * EV * sizeof(float));  // 512 ints

    hipMemsetAsync(flags, 0, NBLK * sizeof(int), stream);
    hipLaunchKernelGGL(mega_kernel, dim3(NBLK), dim3(256), 0, stream,
                       query_value, key_value, w1, b1, w2, wq, bq, wk, bk,
                       value, emb_mask, wo, bo,
                       impute, wd1, bd1, ln_g, ln_b, wd2, bd2,
                       kproj, flags, y, qd);
}

// Round 6
// 115.933 us; speedup vs baseline: 1.3610x; 1.3610x over previous
//
#include <hip/hip_runtime.h>
#include <math.h>

#define B 8
#define SQ 128
#define SK 128
#define IVD 32
#define DIM 32
#define EV 64
#define H 8
#define NH 128
#define DK 8
#define TQ 2
#define KG 8      // k-groups in weighted-sum phase (16 k each)
#define QSCALE 0.3535533905932738f

__device__ __forceinline__ float fast_tanh(float x) {
    const float xc = fminf(fmaxf(x, -10.f), 10.f);
    const float t = __expf(2.f * xc);
    return (t - 1.f) / (t + 1.f);
}

// ---------------- Kernel 1: q/k projections + impute, 2 rows per block ----------------
// blocks [0,512)    : q-row pairs
// blocks [512,1024) : k-row pairs
// blocks [1024,1536): impute-row pairs
__global__ __launch_bounds__(128) void fused1_kernel(
    const float* __restrict__ qv, const float* __restrict__ kv,
    const float* __restrict__ w1, const float* __restrict__ b1,
    const float* __restrict__ w2,
    const float* __restrict__ wq, const float* __restrict__ bqv,
    const float* __restrict__ wk, const float* __restrict__ bkv,
    float* __restrict__ qout, float* __restrict__ kout,
    const float* __restrict__ imp,
    const float* __restrict__ wd1, const float* __restrict__ bd1,
    const float* __restrict__ ln_g, const float* __restrict__ ln_b,
    const float* __restrict__ wd2, const float* __restrict__ bd2,
    float* __restrict__ qd)
{
    const int r = blockIdx.x;
    const int tid = threadIdx.x;

    if (r < 1024) {
        // ---- projection path, rows row0, row0+1 ----
        __shared__ float xs[2][IVD];
        __shared__ float h1[2][NH];
        __shared__ float ev[2][EV];
        __shared__ float part[2][128];
        const float* src; const float* wp; const float* bp; float* dst;
        int row0;
        if (r < 512) { row0 = r * 2;         src = qv; wp = wq; bp = bqv; dst = qout; }
        else         { row0 = (r - 512) * 2; src = kv; wp = wk; bp = bkv; dst = kout; }

        if (tid < 2 * IVD) xs[tid >> 5][tid & 31] = src[row0 * IVD + tid];
        __syncthreads();

        // GEMV1: h1 = tanh(x @ w1 + b1), 128 outputs x 2 rows, shared weight load
        {
            float a0 = b1[tid], a1 = a0;
            #pragma unroll
            for (int i = 0; i < IVD; ++i) {
                const float w = w1[i * NH + tid];
                a0 += xs[0][i] * w; a1 += xs[1][i] * w;
            }
            h1[0][tid] = fast_tanh(a0);
            h1[1][tid] = fast_tanh(a1);
        }
        __syncthreads();

        const int o = tid & 63, hf = tid >> 6;
        // GEMV2: ev = h1 @ w2 (64 outs, dot split in 2 halves, 2 rows share w)
        {
            float c0 = 0.f, c1 = 0.f;
            #pragma unroll 8
            for (int i = hf * 64; i < hf * 64 + 64; ++i) {
                const float w = w2[i * EV + o];
                c0 += h1[0][i] * w; c1 += h1[1][i] * w;
            }
            part[0][tid] = c0; part[1][tid] = c1;
        }
        __syncthreads();
        {
            const int row = tid >> 6, oo = tid & 63;
            ev[row][oo] = part[row][oo] + part[row][oo + 64];
        }
        __syncthreads();
        // GEMV3: dst = ev @ wp + bp
        {
            float c0 = 0.f, c1 = 0.f;
            #pragma unroll 8
            for (int j = hf * 32; j < hf * 32 + 32; ++j) {
                const float w = wp[j * EV + o];
                c0 += ev[0][j] * w; c1 += ev[1][j] * w;
            }
            part[0][tid] = c0; part[1][tid] = c1;
        }
        __syncthreads();
        {
            const int row = tid >> 6, oo = tid & 63;
            dst[(row0 + row) * EV + oo] = part[row][oo] + part[row][oo + 64] + bp[oo];
        }
    } else {
        // ---- impute path, rows bs0, bs0+1 ----
        const int bs0 = (r - 1024) * 2;
        __shared__ float xs2[2][IVD / 2];
        __shared__ float h1b[2][NH];
        __shared__ float red[2][2];

        if (tid < IVD) xs2[tid >> 4][tid & 15] = imp[bs0 * (IVD / 2) + tid];
        __syncthreads();
        float a0 = bd1[tid], a1 = a0;
        #pragma unroll
        for (int i = 0; i < IVD / 2; ++i) {
            const float w = wd1[i * NH + tid];
            a0 += xs2[0][i] * w; a1 += xs2[1][i] * w;
        }

        float s0 = a0, s1 = a1;
        #pragma unroll
        for (int off = 32; off > 0; off >>= 1) {
            s0 += __shfl_down(s0, off, 64);
            s1 += __shfl_down(s1, off, 64);
        }
        if ((tid & 63) == 0) { red[0][tid >> 6] = s0; red[1][tid >> 6] = s1; }
        __syncthreads();
        const float mu0 = (red[0][0] + red[0][1]) * (1.f / NH);
        const float mu1 = (red[1][0] + red[1][1]) * (1.f / NH);
        const float d0 = a0 - mu0, d1 = a1 - mu1;
        float t0 = d0 * d0, t1 = d1 * d1;
        __syncthreads();
        #pragma unroll
        for (int off = 32; off > 0; off >>= 1) {
            t0 += __shfl_down(t0, off, 64);
            t1 += __shfl_down(t1, off, 64);
        }
        if ((tid & 63) == 0) { red[0][tid >> 6] = t0; red[1][tid >> 6] = t1; }
        __syncthreads();
        const float v0 = (red[0][0] + red[0][1]) * (1.f / NH);
        const float v1 = (red[1][0] + red[1][1]) * (1.f / NH);

        const float g = ln_g[tid], bb = ln_b[tid];
        h1b[0][tid] = fmaxf(d0 * rsqrtf(v0 + 1e-5f) * g + bb, 0.f);
        h1b[1][tid] = fmaxf(d1 * rsqrtf(v1 + 1e-5f) * g + bb, 0.f);
        __syncthreads();

        float c0 = bd2[tid], c1 = c0;
        #pragma unroll 8
        for (int j = 0; j < NH; ++j) {
            const float w = wd2[j * NH + tid];
            c0 += h1b[0][j] * w; c1 += h1b[1][j] * w;
        }
        qd[bs0 * NH + tid] = c0;
        qd[(bs0 + 1) * NH + tid] = c1;
    }
}

// ---------------- Kernel 2: masked-softmax attention + output GEMV ----------------
// grid = B * SQ/TQ blocks; each handles TQ=2 q rows of one batch. 256 threads.
// value/mask are loaded straight into registers (coalesced) — no LDS staging.
__global__ __launch_bounds__(256) void attn_kernel(
    const float* __restrict__ qproj, const float* __restrict__ kproj,
    const float* __restrict__ value, const int* __restrict__ mask,
    const float* __restrict__ wo, const float* __restrict__ bo,
    float* __restrict__ y)
{
    const int blk = blockIdx.x;
    const int b = blk >> 6;               // 64 blocks per batch (SQ/TQ)
    const int q0 = (blk & 63) * TQ;
    const int tid = threadIdx.x;

    __shared__ __align__(16) float qs[TQ * EV];         // pre-scaled q rows
    __shared__ __align__(16) float sc[TQ * H * SK];     // exp'd scores (8 KB)
    __shared__ __align__(16) float2 prt[H * KG * DIM];  // partials (16 KB)
    __shared__ __align__(16) float xr[TQ * H * DIM];    // attn out rows
    __shared__ __align__(16) float ypart[2 * TQ * NH];

    const int d = tid & 31, kg = tid >> 5;   // thread owns value-dim d, k-group kg
    const int vbase_off = b * SK * DIM + kg * 16 * DIM + d;

    // direct global->register load of this thread's value/mask slice.
    // lane addresses for fixed j are contiguous in d -> coalesced 128B segments.
    float vv[16], mm[16];
    {
        const float* vbase = value + vbase_off;
        const int*   mbase = mask  + vbase_off;
        #pragma unroll
        for (int j = 0; j < 16; ++j) {
            const float m = (float)mbase[j * DIM];
            mm[j] = m;
            vv[j] = vbase[j * DIM] * m;
        }
    }

    if (tid < TQ * EV) qs[tid] = qproj[(b * SQ + q0) * EV + tid] * QSCALE;
    __syncthreads();

    // scores -> exp directly (no max subtraction: |s| bounded ~O(10), f32-safe,
    // ratios identical to reference softmax)
    #pragma unroll
    for (int i = 0; i < (TQ * H * SK) / 256; ++i) {
        const int p = tid + i * 256;
        const int q = p >> 10, rem = p & 1023, h = rem >> 7, k = rem & 127;
        const float4* kr = (const float4*)(kproj + (b * SK + k) * EV + h * DK);
        const float4* qq = (const float4*)(qs + q * EV + h * DK);
        const float4 k0 = kr[0], k1 = kr[1], qa = qq[0], qb = qq[1];
        const float s = qa.x * k0.x + qa.y * k0.y + qa.z * k0.z + qa.w * k0.w
                      + qb.x * k1.x + qb.y * k1.y + qb.z * k1.z + qb.w * k1.w;
        sc[p] = __expf(s);
    }
    __syncthreads();

    // weighted masked sums over k, split across 8 k-groups
    #pragma unroll
    for (int q = 0; q < TQ; ++q) {
        #pragma unroll
        for (int h = 0; h < H; ++h) {
            const float4* sp = (const float4*)&sc[(q * H + h) * SK + kg * 16];
            float num = 0.f, den = 0.f;
            #pragma unroll
            for (int j4 = 0; j4 < 4; ++j4) {
                const float4 s = sp[j4];
                num += s.x * vv[j4 * 4 + 0] + s.y * vv[j4 * 4 + 1]
                     + s.z * vv[j4 * 4 + 2] + s.w * vv[j4 * 4 + 3];
                den += s.x * mm[j4 * 4 + 0] + s.y * mm[j4 * 4 + 1]
                     + s.z * mm[j4 * 4 + 2] + s.w * mm[j4 * 4 + 3];
            }
            prt[(h * KG + kg) * DIM + d] = make_float2(num, den);
        }
        __syncthreads();
        {   // reduce 8 k-groups; thread -> (h = tid>>5, d = tid&31)
            const int h = tid >> 5;
            float num = 0.f, den = 0.f;
            #pragma unroll
            for (int g = 0; g < KG; ++g) {
                const float2 p2 = prt[(h * KG + g) * DIM + d];
                num += p2.x; den += p2.y;
            }
            xr[q * (H * DIM) + tid] = num / den;
        }
        __syncthreads();
    }

    // y = x @ wo + bo : 256-dot split in halves, wo load shared across TQ rows
    {
        const int n = tid & 127, half = tid >> 7;
        const float* wop = wo + half * 128 * NH + n;
        const float* x0 = xr + half * 128;
        const float* x1 = xr + (H * DIM) + half * 128;
        float a0 = 0.f, a1 = 0.f;
        #pragma unroll 4
        for (int j = 0; j < 128; ++j) {
            const float w = wop[j * NH];
            a0 += w * x0[j];
            a1 += w * x1[j];
        }
        ypart[half * (TQ * NH) + 0 * NH + n] = a0;
        ypart[half * (TQ * NH) + 1 * NH + n] = a1;
    }
    __syncthreads();
    {
        const int q = tid >> 7, n = tid & 127;
        y[(b * SQ + q0 + q) * NH + n] =
            ypart[q * NH + n] + ypart[TQ * NH + q * NH + n] + bo[n];
    }
}

extern "C" void kernel_launch(void* const* d_in, const int* in_sizes, int n_in,
                              void* d_out, int out_size, void* d_ws, size_t ws_size,
                              hipStream_t stream) {
    const float* query_value = (const float*)d_in[0];
    const float* key_value   = (const float*)d_in[1];
    const float* value       = (const float*)d_in[2];
    const float* impute      = (const float*)d_in[3];
    const int*   emb_mask    = (const int*)d_in[4];
    const float* w1   = (const float*)d_in[5];
    const float* b1   = (const float*)d_in[6];
    const float* w2   = (const float*)d_in[7];
    const float* wq   = (const float*)d_in[8];
    const float* bq   = (const float*)d_in[9];
    const float* wk   = (const float*)d_in[10];
    const float* bk   = (const float*)d_in[11];
    const float* wo   = (const float*)d_in[12];
    const float* bo   = (const float*)d_in[13];
    const float* wd1  = (const float*)d_in[14];
    const float* bd1  = (const float*)d_in[15];
    const float* ln_g = (const float*)d_in[16];
    const float* ln_b = (const float*)d_in[17];
    const float* wd2  = (const float*)d_in[18];
    const float* bd2  = (const float*)d_in[19];

    float* y  = (float*)d_out;                 // (B,SQ,NH)
    float* qd = y + B * SQ * NH;               // (B,SQ,NH)

    float* qproj = (float*)d_ws;               // (B,SQ,EV)
    float* kproj = qproj + B * SQ * EV;        // (B,SK,EV)

    hipLaunchKernelGGL(fused1_kernel, dim3(1536), dim3(128), 0, stream,
                       query_value, key_value, w1, b1, w2, wq, bq, wk, bk,
                       qproj, kproj,
                       impute, wd1, bd1, ln_g, ln_b, wd2, bd2, qd);
    hipLaunchKernelGGL(attn_kernel, dim3(B * SQ / TQ), dim3(256), 0, stream,
                       qproj, kproj, value, emb_mask, wo, bo, y);
}